// Round 3
// baseline (347.755 us; speedup 1.0000x reference)
//
#include <hip/hip_runtime.h>
#include <cstdint>
#include <cstddef>

// InterpAttentionKHeadsNet — fp16 MFMA, round 3.
// vs round 2: (1) in-place single activation buffer (read-all -> barrier ->
// write-all), (2) in-register softmax via shfl_xor (no Qs LDS round-trip),
// (3) 8B-granule XOR swizzle: 16 lanes cover all 32 banks exactly once,
// (4) k-major-packed weights for coalesced A-frag loads.
// LDS 74KB -> ~38.5KB => 4 blocks/CU (16 waves/CU).

#define NLAT 256
#define KNB 16
#define QB 4
#define MROWS 64      // QB*KNB rows per block
#define ROWB 576      // 72 granules * 8B per row (64 latent + 8 rel/pad)

typedef float    f32x4 __attribute__((ext_vector_type(4)));
typedef _Float16 f16x8 __attribute__((ext_vector_type(8)));
typedef _Float16 f16x4 __attribute__((ext_vector_type(4)));

// 8-byte-granule swizzle: granule g of row -> g ^ (row&15). 16 rows at fixed g
// map to 16 distinct even bank-starts covering all 32 banks exactly once.
__device__ __forceinline__ int swz8(int g, int row) {
  return (g < 64) ? (g ^ (row & 15)) : (64 + ((g - 64) ^ (row & 7)));
}
__device__ __forceinline__ int lb8(int row, int g) {
  return row * ROWB + swz8(g, row) * 8;
}

struct Smem {
  unsigned char buf[MROWS * ROWB];  // 36864 B, in-place activations
  float Sp[4][MROWS];               // per-wave attention partials
  float Sv[MROWS];                  // S[m] = wv8 . H3[m]
  int sidx[MROWS];
  int is64;
};

// In-place layer: C'[ch][m] = Wp x H^T; all reads -> barrier -> bias/relu/write.
// Wp is k-major packed: Wp[(kc*256 + ch)*8 + e] = W[ch][kc*8+e].
__device__ __forceinline__ void layer_mfma(
    unsigned char* buf, const unsigned short* __restrict__ Wp,
    const float* __restrict__ bias, const float* __restrict__ W1tail,
    int lane, int wave, bool relu)
{
  const _Float16* W = (const _Float16*)Wp;
  const int lm = lane & 15, lk = lane >> 4;
  f32x4 acc[4][4];
#pragma unroll
  for (int i = 0; i < 4; ++i)
#pragma unroll
    for (int j = 0; j < 4; ++j) acc[i][j] = (f32x4){0.f, 0.f, 0.f, 0.f};

#pragma unroll
  for (int ks = 0; ks < 8; ++ks) {
    const int kc = ks * 4 + lk;
    f16x8 a[4], bf[4];
#pragma unroll
    for (int ct = 0; ct < 4; ++ct) {
      const int ch = wave * 64 + ct * 16 + lm;
      a[ct] = *(const f16x8*)(W + ((size_t)kc * 256 + ch) * 8);  // coalesced
    }
#pragma unroll
    for (int mt = 0; mt < 4; ++mt) {
      const int row = mt * 16 + lm;
      f16x4 lo = *(const f16x4*)(buf + lb8(row, kc * 2));
      f16x4 hi = *(const f16x4*)(buf + lb8(row, kc * 2 + 1));
      bf[mt] = __builtin_shufflevector(lo, hi, 0, 1, 2, 3, 4, 5, 6, 7);
    }
#pragma unroll
    for (int ct = 0; ct < 4; ++ct)
#pragma unroll
      for (int mt = 0; mt < 4; ++mt)
        acc[ct][mt] = __builtin_amdgcn_mfma_f32_16x16x32_f16(a[ct], bf[mt], acc[ct][mt], 0, 0, 0);
  }
  if (W1tail) {  // 9th k-step: k=256..287 (rel channels, zero padded)
    f16x8 a[4], bf[4];
#pragma unroll
    for (int ct = 0; ct < 4; ++ct) {
      f16x8 v = {0, 0, 0, 0, 0, 0, 0, 0};
      if (lk == 0) {
        const int ch = wave * 64 + ct * 16 + lm;
        const float* wt = W1tail + (size_t)ch * 259 + 256;
        v[0] = (_Float16)wt[0]; v[1] = (_Float16)wt[1]; v[2] = (_Float16)wt[2];
      }
      a[ct] = v;
    }
#pragma unroll
    for (int mt = 0; mt < 4; ++mt) {
      const int row = mt * 16 + lm;
      f16x4 lo = *(const f16x4*)(buf + lb8(row, 64 + 2 * lk));
      f16x4 hi = *(const f16x4*)(buf + lb8(row, 65 + 2 * lk));
      bf[mt] = __builtin_shufflevector(lo, hi, 0, 1, 2, 3, 4, 5, 6, 7);
    }
#pragma unroll
    for (int ct = 0; ct < 4; ++ct)
#pragma unroll
      for (int mt = 0; mt < 4; ++mt)
        acc[ct][mt] = __builtin_amdgcn_mfma_f32_16x16x32_f16(a[ct], bf[mt], acc[ct][mt], 0, 0, 0);
  }
  __syncthreads();  // all reads done -> safe to overwrite in place
#pragma unroll
  for (int ct = 0; ct < 4; ++ct) {
    const int ch0 = wave * 64 + ct * 16 + lk * 4;
    const float4 bs = *(const float4*)(bias + ch0);
#pragma unroll
    for (int mt = 0; mt < 4; ++mt) {
      const int row = mt * 16 + lm;
      f16x4 v;
      float bb[4] = {bs.x, bs.y, bs.z, bs.w};
#pragma unroll
      for (int r = 0; r < 4; ++r) {
        float x = acc[ct][mt][r] + bb[r];
        if (relu) x = fmaxf(x, 0.f);
        v[r] = (_Float16)x;
      }
      *(f16x4*)(buf + row * ROWB + swz8(ch0 >> 2, row) * 8) = v;
    }
  }
}

extern "C" __global__ __launch_bounds__(256, 4)
void interp_mfma(const float* __restrict__ latents,
                 const float* __restrict__ pts,
                 const float* __restrict__ ptsq,
                 const void*  __restrict__ proj,
                 const unsigned short* __restrict__ Lt_u,   // fp16 [B][N][256]
                 const float* __restrict__ W1f,             // fp32 [256][259]
                 const unsigned short* __restrict__ W1p,
                 const unsigned short* __restrict__ W2p,
                 const unsigned short* __restrict__ W3p,
                 const unsigned short* __restrict__ Wqp,    // packed [32][64][8]
                 const float* __restrict__ b1, const float* __restrict__ b2,
                 const float* __restrict__ b3, const float* __restrict__ bq,
                 const float* __restrict__ wv8, const float* __restrict__ c0p,
                 float* __restrict__ out,
                 int N, int NQ, int use_lt)
{
  __shared__ Smem sm;
  const int tid = threadIdx.x;
  const int bid = blockIdx.x;
  const int lane = tid & 63, wave = tid >> 6;
  const int lm = lane & 15, lk = lane >> 4;

  if (tid == 0) {
    const int* p = (const int*)proj;
    int z = 1;
    for (int i = 0; i < 64; ++i) z &= (p[2 * i + 1] == 0);
    sm.is64 = z;
  }
  __syncthreads();
  if (tid < MROWS) {
    long long g = (long long)bid * QB + (tid >> 4);
    long long base = g * KNB + (tid & 15);
    sm.sidx[tid] = sm.is64 ? (int)((const long long*)proj)[base]
                           : ((const int*)proj)[base];
  }
  __syncthreads();

  // ---- gather: 64 granules (8B = 4ch) per row, interleaved to avoid conflicts
  {
    const int row = tid >> 2, part = tid & 3;
    const int id = sm.sidx[row];
    const long long g = (long long)bid * QB + (row >> 4);
    const int b = (int)(g / NQ);
    if (use_lt) {
      const _Float16* src = (const _Float16*)Lt_u + ((size_t)b * N + id) * NLAT;
#pragma unroll
      for (int j = 0; j < 16; ++j) {
        const int gr = part + j * 4;
        *(f16x4*)(sm.buf + lb8(row, gr)) = *(const f16x4*)(src + gr * 4);
      }
    } else {
      for (int j = 0; j < 16; ++j) {
        const int gr = part + j * 4;
        f16x4 v;
#pragma unroll
        for (int e = 0; e < 4; ++e)
          v[e] = (_Float16)latents[((size_t)b * NLAT + gr * 4 + e) * N + id];
        *(f16x4*)(sm.buf + lb8(row, gr)) = v;
      }
    }
    const f16x4 z = {0, 0, 0, 0};
    if (part == 0) {
      const int nq = (int)(g - (long long)b * NQ);
      f16x4 v = {0, 0, 0, 0};
#pragma unroll
      for (int j = 0; j < 3; ++j)
        v[j] = (_Float16)(ptsq[((size_t)b * 3 + j) * NQ + nq]
                        - pts[((size_t)b * 3 + j) * N + id]);
      *(f16x4*)(sm.buf + lb8(row, 64)) = v;
      *(f16x4*)(sm.buf + lb8(row, 65)) = z;
    } else {
      *(f16x4*)(sm.buf + lb8(row, 64 + 2 * part)) = z;
      *(f16x4*)(sm.buf + lb8(row, 65 + 2 * part)) = z;
    }
  }
  __syncthreads();

  layer_mfma(sm.buf, W1p, b1, W1f, lane, wave, true);
  __syncthreads();
  layer_mfma(sm.buf, W2p, b2, nullptr, lane, wave, true);
  __syncthreads();
  layer_mfma(sm.buf, W3p, b3, nullptr, lane, wave, true);
  __syncthreads();

  // ---- Q heads (wave owns 16 heads) + S = wv8.H3, all from buf (read-only)
  f32x4 qacc[4];
#pragma unroll
  for (int mt = 0; mt < 4; ++mt) qacc[mt] = (f32x4){0.f, 0.f, 0.f, 0.f};
  {
    const _Float16* Wq16 = (const _Float16*)Wqp;
#pragma unroll
    for (int ks = 0; ks < 8; ++ks) {
      const int kc = ks * 4 + lk;
      f16x8 a = *(const f16x8*)(Wq16 + ((size_t)kc * 64 + wave * 16 + lm) * 8);
#pragma unroll
      for (int mt = 0; mt < 4; ++mt) {
        const int row = mt * 16 + lm;
        f16x4 lo = *(const f16x4*)(sm.buf + lb8(row, kc * 2));
        f16x4 hi = *(const f16x4*)(sm.buf + lb8(row, kc * 2 + 1));
        f16x8 bf = __builtin_shufflevector(lo, hi, 0, 1, 2, 3, 4, 5, 6, 7);
        qacc[mt] = __builtin_amdgcn_mfma_f32_16x16x32_f16(a, bf, qacc[mt], 0, 0, 0);
      }
    }
  }
  {  // S partial: lane (lk,lm) covers row wave*16+lm, chunks c = cc*4+lk
    const int row = wave * 16 + lm;
    float sacc = 0.f;
#pragma unroll
    for (int cc = 0; cc < 8; ++cc) {
      const int c = cc * 4 + lk;
      f16x4 lo = *(const f16x4*)(sm.buf + lb8(row, 2 * c));
      f16x4 hi = *(const f16x4*)(sm.buf + lb8(row, 2 * c + 1));
      const float4 w0 = *(const float4*)(wv8 + c * 8);
      const float4 w1 = *(const float4*)(wv8 + c * 8 + 4);
      sacc += (float)lo[0] * w0.x + (float)lo[1] * w0.y
            + (float)lo[2] * w0.z + (float)lo[3] * w0.w;
      sacc += (float)hi[0] * w1.x + (float)hi[1] * w1.y
            + (float)hi[2] * w1.z + (float)hi[3] * w1.w;
    }
    sacc += __shfl_xor(sacc, 16);
    sacc += __shfl_xor(sacc, 32);
    if (lk == 0) sm.Sv[row] = sacc;
  }

  // ---- in-register softmax over nb (= lm lanes) per head; mean over heads
  {
    float bqv[4];
#pragma unroll
    for (int r = 0; r < 4; ++r) bqv[r] = bq[wave * 16 + lk * 4 + r];
#pragma unroll
    for (int mt = 0; mt < 4; ++mt) {
      float sw = 0.f;
#pragma unroll
      for (int r = 0; r < 4; ++r) {
        const float qv = qacc[mt][r] + bqv[r];
        float mx = qv;
#pragma unroll
        for (int msk = 1; msk < 16; msk <<= 1) mx = fmaxf(mx, __shfl_xor(mx, msk));
        const float e = __expf(qv - mx);
        float s = e;
#pragma unroll
        for (int msk = 1; msk < 16; msk <<= 1) s += __shfl_xor(s, msk);
        sw += e / s;
      }
      sw += __shfl_xor(sw, 16);   // sum over lk groups (16 heads of this wave)
      sw += __shfl_xor(sw, 32);
      if (lk == 0) sm.Sp[wave][mt * 16 + lm] = sw;
    }
  }
  __syncthreads();

  // ---- out[q] = sum_nb att[m] * S[m] + c0, wave w handles q = w
  {
    const int m = wave * 16 + (lane & 15);
    const float a = (sm.Sp[0][m] + sm.Sp[1][m] + sm.Sp[2][m] + sm.Sp[3][m]) * (1.f / 64.f);
    float val = a * sm.Sv[m];
#pragma unroll
    for (int msk = 1; msk < 16; msk <<= 1) val += __shfl_xor(val, msk);
    if (lane == 0) out[(long long)bid * QB + wave] = val + c0p[0];
  }
}

// ---- prep: fp32 -> fp16 k-major pack; wv8 = W8*Wv fold; c0 = b8 + W8.bv ----
extern "C" __global__ void prep_w(const float* __restrict__ W1, const float* __restrict__ W2,
                                  const float* __restrict__ W3, const float* __restrict__ Wq,
                                  const float* __restrict__ Wv, const float* __restrict__ W8,
                                  const float* __restrict__ bv, const float* __restrict__ b8,
                                  unsigned short* W1p, unsigned short* W2p,
                                  unsigned short* W3p, unsigned short* Wqp,
                                  float* wv8, float* c0) {
  const int t = blockIdx.x * 256 + threadIdx.x;
  union { _Float16 h; unsigned short u; } cv;
  if (t < 65536) {
    const int ch = t >> 8, k = t & 255;
    const int dst = (((k >> 3) << 8) + ch) * 8 + (k & 7);  // [kc][ch][e]
    cv.h = (_Float16)W1[(size_t)ch * 259 + k]; W1p[dst] = cv.u;
    cv.h = (_Float16)W2[t]; W2p[dst] = cv.u;
    cv.h = (_Float16)W3[t]; W3p[dst] = cv.u;
  }
  if (t < 16384) {
    const int hd = t >> 8, k = t & 255;
    cv.h = (_Float16)Wq[t];
    Wqp[(((k >> 3) << 6) + hd) * 8 + (k & 7)] = cv.u;     // [kc][head][e]
  }
  if (t < 256) {
    float s = 0.f;
    for (int o = 0; o < 256; ++o) s += Wv[(size_t)o * 256 + t] * W8[o];
    wv8[t] = s;
  }
  if (t == 0) {
    float s = 0.f;
    for (int o = 0; o < 256; ++o) s += bv[o] * W8[o];
    c0[0] = s + b8[0];
  }
}

// ---- transpose latents [B][256][N] -> fp16 [B][N][256] ----
extern "C" __global__ void transp(const float* __restrict__ latents,
                                  unsigned short* __restrict__ Lt, int N) {
  __shared__ unsigned short tile[256][68];
  const int b = blockIdx.y, n0 = blockIdx.x * 64, tid = threadIdx.x;
  const int nl = tid & 63;
  union { _Float16 h; unsigned short u; } cv;
  for (int c = tid >> 6; c < 256; c += 4) {
    const int n = n0 + nl;
    float v = (n < N) ? latents[((size_t)b * NLAT + c) * N + n] : 0.f;
    cv.h = (_Float16)v;
    tile[c][nl] = cv.u;
  }
  __syncthreads();
  const int nr = tid >> 2, cg = (tid & 3) * 64;
  const int n = n0 + nr;
  if (n < N) {
    for (int cc = 0; cc < 64; cc += 8) {
      f16x8 v;
#pragma unroll
      for (int j = 0; j < 8; ++j) {
        union { unsigned short u; _Float16 h; } bk;
        bk.u = tile[cg + cc + j][nr];
        v[j] = bk.h;
      }
      *(f16x8*)((_Float16*)Lt + ((size_t)b * N + n) * NLAT + cg + cc) = v;
    }
  }
}

extern "C" void kernel_launch(void* const* d_in, const int* in_sizes, int n_in,
                              void* d_out, int out_size, void* d_ws, size_t ws_size,
                              hipStream_t stream) {
  (void)n_in; (void)out_size;
  const float* latents = (const float*)d_in[0];
  const float* pts     = (const float*)d_in[1];
  const float* ptsq    = (const float*)d_in[2];
  const void*  proj    = d_in[3];
  const float* W1 = (const float*)d_in[4];  const float* b1 = (const float*)d_in[5];
  const float* W2 = (const float*)d_in[6];  const float* b2 = (const float*)d_in[7];
  const float* W3 = (const float*)d_in[8];  const float* b3 = (const float*)d_in[9];
  const float* Wq = (const float*)d_in[10]; const float* bq = (const float*)d_in[11];
  const float* Wv = (const float*)d_in[12]; const float* bv = (const float*)d_in[13];
  const float* W8 = (const float*)d_in[14]; const float* b8 = (const float*)d_in[15];
  float* out = (float*)d_out;

  const int B  = 2;
  const int N  = in_sizes[1] / (3 * B);
  const int NQ = in_sizes[2] / (3 * B);

  size_t off = 0;
  auto alloc = [&](size_t bytes) -> char* {
    char* p = (char*)d_ws + off;
    off += (bytes + 255) & ~(size_t)255;
    return p;
  };
  unsigned short* W1p = (unsigned short*)alloc(65536 * 2);
  unsigned short* W2p = (unsigned short*)alloc(65536 * 2);
  unsigned short* W3p = (unsigned short*)alloc(65536 * 2);
  unsigned short* Wqp = (unsigned short*)alloc(16384 * 2);
  float* wv8 = (float*)alloc(256 * 4);
  float* c0  = (float*)alloc(4);
  const size_t lt_bytes = (size_t)B * N * NLAT * 2;
  unsigned short* Lt = (unsigned short*)((char*)d_ws + off);
  const int use_lt = (off + lt_bytes <= ws_size) ? 1 : 0;

  hipLaunchKernelGGL(prep_w, dim3(256), dim3(256), 0, stream,
                     W1, W2, W3, Wq, Wv, W8, bv, b8, W1p, W2p, W3p, Wqp, wv8, c0);
  if (use_lt)
    hipLaunchKernelGGL(transp, dim3((N + 63) / 64, B), dim3(256), 0, stream,
                       latents, Lt, N);
  const int nblocks = (B * NQ + QB - 1) / QB;
  hipLaunchKernelGGL(interp_mfma, dim3(nblocks), dim3(256), 0, stream,
                     latents, pts, ptsq, proj, Lt, W1, W1p, W2p, W3p, Wqp,
                     b1, b2, b3, bq, wv8, c0, out, N, NQ, use_lt);
}

// Round 5
// 218.912 us; speedup vs baseline: 1.5886x; 1.5886x over previous
//
#include <hip/hip_runtime.h>
#include <cstdint>
#include <cstddef>

// InterpAttentionKHeadsNet — fp16 MFMA, round 5 (= round 4 + Q-address fix).
// Round 4 NaN root cause: Q-phase read Wqh (row-major [64][256]) with stale
// packed-layout offsets (lk*64, ks*256) -> OOB into unwritten ws padding ->
// fp16 NaN garbage into MFMA. Correct offset: head*512 + ks*64 + lk*16.
// Structure: (1) launch_bounds(256,3) => no register spills, (2) LDS swizzle
// phys(g,row)=(g&~7)|((g&7)^(row&7)): all ds addresses are base + immediate,
// 2 lanes/bank (free per m136), (3) k-major packed weights, immediate offsets.

#define NLAT 256
#define KNB 16
#define QB 4
#define MROWS 64      // QB*KNB rows per block
#define ROWB 576      // 72 granules * 8B (64 latent + 8 rel/pad)

typedef float    f32x4 __attribute__((ext_vector_type(4)));
typedef _Float16 f16x8 __attribute__((ext_vector_type(8)));
typedef _Float16 f16x4 __attribute__((ext_vector_type(4)));

struct Smem {
  unsigned char buf[MROWS * ROWB];  // 36864 B, in-place activations
  float Sp[4][MROWS];
  float Sv[MROWS];
  int sidx[MROWS];
  int is64;
};

// In-place layer: C'[ch][m] = Wp x H^T; reads -> barrier -> bias/relu/write.
// Wp k-major: byte addr of (kc, ch) frag = kc*4096 + ch*16.
__device__ __forceinline__ void layer_mfma(
    unsigned char* __restrict__ buf, const unsigned short* __restrict__ Wp,
    const float* __restrict__ bias, const float* __restrict__ W1f,
    int lane, int wave, bool relu)
{
  const int lm = lane & 15, lk = lane >> 4, rk = lm & 7;
  // B-frag read bases: row=mt*16+lm, granule g=8ks+2lk+h ->
  // byte = lm*576 + ((2lk+h)^rk)*8  +  mt*9216 + ks*64  (immediates)
  const char* bp0 = (const char*)buf + lm * 576 + ((2 * lk) ^ rk) * 8;
  const char* bp1 = (const char*)buf + lm * 576 + ((2 * lk + 1) ^ rk) * 8;
  const char* wbase = (const char*)Wp + lk * 4096 + (wave * 64 + lm) * 16;

  f32x4 acc[4][4];
#pragma unroll
  for (int i = 0; i < 4; ++i)
#pragma unroll
    for (int j = 0; j < 4; ++j) acc[i][j] = (f32x4){0.f, 0.f, 0.f, 0.f};

#pragma unroll
  for (int ks = 0; ks < 8; ++ks) {
    const char* wk = wbase + ks * 16384;
    f16x8 a[4], bf[4];
#pragma unroll
    for (int ct = 0; ct < 4; ++ct)
      a[ct] = *(const f16x8*)(wk + ct * 256);
#pragma unroll
    for (int mt = 0; mt < 4; ++mt) {
      f16x4 lo = *(const f16x4*)(bp0 + mt * 9216 + ks * 64);
      f16x4 hi = *(const f16x4*)(bp1 + mt * 9216 + ks * 64);
      bf[mt] = __builtin_shufflevector(lo, hi, 0, 1, 2, 3, 4, 5, 6, 7);
    }
#pragma unroll
    for (int ct = 0; ct < 4; ++ct)
#pragma unroll
      for (int mt = 0; mt < 4; ++mt)
        acc[ct][mt] = __builtin_amdgcn_mfma_f32_16x16x32_f16(a[ct], bf[mt], acc[ct][mt], 0, 0, 0);
  }
  if (W1f) {  // tail k-step: k=256..287 (rel, zero-padded); B granules 64..71
    f16x8 a[4], bf[4];
#pragma unroll
    for (int ct = 0; ct < 4; ++ct) {
      f16x8 v = {0, 0, 0, 0, 0, 0, 0, 0};
      if (lk == 0) {
        const int ch = wave * 64 + ct * 16 + lm;
        const float* wt = W1f + (size_t)ch * 259 + 256;
        v[0] = (_Float16)wt[0]; v[1] = (_Float16)wt[1]; v[2] = (_Float16)wt[2];
      }
      a[ct] = v;
    }
#pragma unroll
    for (int mt = 0; mt < 4; ++mt) {
      f16x4 lo = *(const f16x4*)(bp0 + mt * 9216 + 512);
      f16x4 hi = *(const f16x4*)(bp1 + mt * 9216 + 512);
      bf[mt] = __builtin_shufflevector(lo, hi, 0, 1, 2, 3, 4, 5, 6, 7);
    }
#pragma unroll
    for (int ct = 0; ct < 4; ++ct)
#pragma unroll
      for (int mt = 0; mt < 4; ++mt)
        acc[ct][mt] = __builtin_amdgcn_mfma_f32_16x16x32_f16(a[ct], bf[mt], acc[ct][mt], 0, 0, 0);
  }
  __syncthreads();  // all reads done -> safe to overwrite in place
  // epilogue write: quad g = wave*16 + ct*4 + lk at row mt*16+lm ->
  // byte = lm*576 + wave*128 + (((ct&1)*4+lk)^rk)*8 + mt*9216 + (ct>>1)*64
  char* we0 = (char*)buf + lm * 576 + wave * 128 + (lk ^ rk) * 8;
  char* we1 = (char*)buf + lm * 576 + wave * 128 + ((4 + lk) ^ rk) * 8;
#pragma unroll
  for (int ct = 0; ct < 4; ++ct) {
    const int ch0 = wave * 64 + ct * 16 + lk * 4;
    const float4 bs = *(const float4*)(bias + ch0);
    const float bb[4] = {bs.x, bs.y, bs.z, bs.w};
    char* web = ((ct & 1) ? we1 : we0) + (ct >> 1) * 64;
#pragma unroll
    for (int mt = 0; mt < 4; ++mt) {
      f16x4 v;
#pragma unroll
      for (int r = 0; r < 4; ++r) {
        float x = acc[ct][mt][r] + bb[r];
        if (relu) x = fmaxf(x, 0.f);
        v[r] = (_Float16)x;
      }
      *(f16x4*)(web + mt * 9216) = v;
    }
  }
}

extern "C" __global__ __launch_bounds__(256, 3)
void interp_mfma(const float* __restrict__ latents,
                 const float* __restrict__ pts,
                 const float* __restrict__ ptsq,
                 const void*  __restrict__ proj,
                 const unsigned short* __restrict__ Lt_u,   // fp16 [B][N][256]
                 const float* __restrict__ W1f,             // fp32 [256][259]
                 const unsigned short* __restrict__ W1p,
                 const unsigned short* __restrict__ W2p,
                 const unsigned short* __restrict__ W3p,
                 const unsigned short* __restrict__ Wqh,    // fp16 [64][256] row-major
                 const float* __restrict__ b1, const float* __restrict__ b2,
                 const float* __restrict__ b3, const float* __restrict__ bq,
                 const float* __restrict__ wv8, const float* __restrict__ c0p,
                 float* __restrict__ out,
                 int N, int NQ, int use_lt)
{
  __shared__ Smem sm;
  const int tid = threadIdx.x;
  const int bid = blockIdx.x;
  const int lane = tid & 63, wave = tid >> 6;
  const int lm = lane & 15, lk = lane >> 4, rk = lm & 7;

  if (tid == 0) {
    const int* p = (const int*)proj;
    int z = 1;
    for (int i = 0; i < 64; ++i) z &= (p[2 * i + 1] == 0);
    sm.is64 = z;
  }
  __syncthreads();
  if (tid < MROWS) {
    long long g = (long long)bid * QB + (tid >> 4);
    long long base = g * KNB + (tid & 15);
    sm.sidx[tid] = sm.is64 ? (int)((const long long*)proj)[base]
                           : ((const int*)proj)[base];
  }
  __syncthreads();

  // ---- gather: thread (row=tid>>2, part=tid&3) handles granules 2part+h+8jj
  {
    const int row = tid >> 2, part = tid & 3, rg = row & 7;
    const int id = sm.sidx[row];
    const long long g = (long long)bid * QB + (row >> 4);
    const int b = (int)(g / NQ);
    char* g0 = (char*)sm.buf + row * 576 + ((2 * part) ^ rg) * 8;
    char* g1 = (char*)sm.buf + row * 576 + ((2 * part + 1) ^ rg) * 8;
    if (use_lt) {
      const _Float16* src = (const _Float16*)Lt_u + ((size_t)b * N + id) * NLAT + part * 8;
#pragma unroll
      for (int jj = 0; jj < 8; ++jj) {
        f16x8 v = *(const f16x8*)(src + jj * 32);   // granules 2part+8jj, +1
        f16x4 vl = {v[0], v[1], v[2], v[3]}, vh = {v[4], v[5], v[6], v[7]};
        *(f16x4*)(g0 + jj * 64) = vl;
        *(f16x4*)(g1 + jj * 64) = vh;
      }
    } else {
      for (int jj = 0; jj < 8; ++jj) {
        f16x4 vl, vh;
#pragma unroll
        for (int e = 0; e < 4; ++e) {
          vl[e] = (_Float16)latents[((size_t)b * NLAT + (2 * part + 8 * jj) * 4 + e) * N + id];
          vh[e] = (_Float16)latents[((size_t)b * NLAT + (2 * part + 1 + 8 * jj) * 4 + e) * N + id];
        }
        *(f16x4*)(g0 + jj * 64) = vl;
        *(f16x4*)(g1 + jj * 64) = vh;
      }
    }
    // rel/pad granules 64..71: thread part writes g = 64+2part, 65+2part
    const f16x4 z = {0, 0, 0, 0};
    f16x4 v0 = z;
    if (part == 0) {
      const int nq = (int)(g - (long long)b * NQ);
#pragma unroll
      for (int j = 0; j < 3; ++j)
        v0[j] = (_Float16)(ptsq[((size_t)b * 3 + j) * NQ + nq]
                         - pts[((size_t)b * 3 + j) * N + id]);
    }
    *(f16x4*)((char*)sm.buf + row * 576 + 512 + ((2 * part) ^ rg) * 8) = v0;
    *(f16x4*)((char*)sm.buf + row * 576 + 512 + ((2 * part + 1) ^ rg) * 8) = z;
  }
  __syncthreads();

  layer_mfma(sm.buf, W1p, b1, W1f, lane, wave, true);
  __syncthreads();
  layer_mfma(sm.buf, W2p, b2, nullptr, lane, wave, true);
  __syncthreads();
  layer_mfma(sm.buf, W3p, b3, nullptr, lane, wave, true);
  __syncthreads();

  // ---- Q heads (wave owns 16 heads): C'[head][m] via MFMA, acc in regs
  const char* bp0 = (const char*)sm.buf + lm * 576 + ((2 * lk) ^ rk) * 8;
  const char* bp1 = (const char*)sm.buf + lm * 576 + ((2 * lk + 1) ^ rk) * 8;
  f32x4 qacc[4];
#pragma unroll
  for (int mt = 0; mt < 4; ++mt) qacc[mt] = (f32x4){0.f, 0.f, 0.f, 0.f};
  {
    // head row h = wave*16+lm (512 B/row); k-chunk kc = ks*4+lk ->
    // byte = h*512 + ks*64 + lk*16   (FIX vs round 4: was lk*64 + ks*256)
    const char* wqb = (const char*)Wqh + (wave * 16 + lm) * 512 + lk * 16;
#pragma unroll
    for (int ks = 0; ks < 8; ++ks) {
      f16x8 a = *(const f16x8*)(wqb + ks * 64);
#pragma unroll
      for (int mt = 0; mt < 4; ++mt) {
        f16x4 lo = *(const f16x4*)(bp0 + mt * 9216 + ks * 64);
        f16x4 hi = *(const f16x4*)(bp1 + mt * 9216 + ks * 64);
        f16x8 bf = __builtin_shufflevector(lo, hi, 0, 1, 2, 3, 4, 5, 6, 7);
        qacc[mt] = __builtin_amdgcn_mfma_f32_16x16x32_f16(a, bf, qacc[mt], 0, 0, 0);
      }
    }
  }
  // ---- S[m] = wv8 . H3[m] for rows wave*16+lm (chunks c = cc*4+lk)
  {
    const char* sp0 = bp0 + wave * 9216;
    const char* sp1 = bp1 + wave * 9216;
    float sacc = 0.f;
#pragma unroll
    for (int cc = 0; cc < 8; ++cc) {
      f16x4 lo = *(const f16x4*)(sp0 + cc * 64);
      f16x4 hi = *(const f16x4*)(sp1 + cc * 64);
      const int c = cc * 4 + lk;
      const float4 w0 = *(const float4*)(wv8 + c * 8);
      const float4 w1 = *(const float4*)(wv8 + c * 8 + 4);
      sacc += (float)lo[0] * w0.x + (float)lo[1] * w0.y
            + (float)lo[2] * w0.z + (float)lo[3] * w0.w;
      sacc += (float)hi[0] * w1.x + (float)hi[1] * w1.y
            + (float)hi[2] * w1.z + (float)hi[3] * w1.w;
    }
    sacc += __shfl_xor(sacc, 16);
    sacc += __shfl_xor(sacc, 32);
    if (lk == 0) sm.Sv[wave * 16 + lm] = sacc;
  }

  // ---- in-register softmax over nb (= lm lanes) per head; mean over heads
  {
    float bqv[4];
#pragma unroll
    for (int r = 0; r < 4; ++r) bqv[r] = bq[wave * 16 + lk * 4 + r];
#pragma unroll
    for (int mt = 0; mt < 4; ++mt) {
      float sw = 0.f;
#pragma unroll
      for (int r = 0; r < 4; ++r) {
        const float qv = qacc[mt][r] + bqv[r];
        float mx = qv;
#pragma unroll
        for (int msk = 1; msk < 16; msk <<= 1) mx = fmaxf(mx, __shfl_xor(mx, msk));
        const float e = __expf(qv - mx);
        float s = e;
#pragma unroll
        for (int msk = 1; msk < 16; msk <<= 1) s += __shfl_xor(s, msk);
        sw += e / s;
      }
      sw += __shfl_xor(sw, 16);
      sw += __shfl_xor(sw, 32);
      if (lk == 0) sm.Sp[wave][mt * 16 + lm] = sw;
    }
  }
  __syncthreads();

  // ---- out[q] = sum_nb att[m]*S[m] + c0; wave w handles q = w
  {
    const int m = wave * 16 + lm;
    const float a = (sm.Sp[0][m] + sm.Sp[1][m] + sm.Sp[2][m] + sm.Sp[3][m]) * (1.f / 64.f);
    float val = a * sm.Sv[m];
#pragma unroll
    for (int msk = 1; msk < 16; msk <<= 1) val += __shfl_xor(val, msk);
    if (lane == 0) out[(long long)bid * QB + wave] = val + c0p[0];
  }
}

// ---- prep: fp32 -> fp16 packs; wv8 = W8*Wv fold; c0 = b8 + W8.bv ----
extern "C" __global__ void prep_w(const float* __restrict__ W1, const float* __restrict__ W2,
                                  const float* __restrict__ W3, const float* __restrict__ Wq,
                                  const float* __restrict__ Wv, const float* __restrict__ W8,
                                  const float* __restrict__ bv, const float* __restrict__ b8,
                                  unsigned short* W1p, unsigned short* W2p,
                                  unsigned short* W3p, unsigned short* Wqh,
                                  float* wv8, float* c0) {
  const int t = blockIdx.x * 256 + threadIdx.x;
  union { _Float16 h; unsigned short u; } cv;
  if (t < 65536) {
    const int ch = t >> 8, k = t & 255;
    const int dst = (((k >> 3) << 8) + ch) * 8 + (k & 7);  // [kc][ch][e]
    cv.h = (_Float16)W1[(size_t)ch * 259 + k]; W1p[dst] = cv.u;
    cv.h = (_Float16)W2[t]; W2p[dst] = cv.u;
    cv.h = (_Float16)W3[t]; W3p[dst] = cv.u;
  }
  if (t < 16384) { cv.h = (_Float16)Wq[t]; Wqh[t] = cv.u; }  // row-major
  if (t < 256) {
    float s = 0.f;
    for (int o = 0; o < 256; ++o) s += Wv[(size_t)o * 256 + t] * W8[o];
    wv8[t] = s;
  }
  if (t == 0) {
    float s = 0.f;
    for (int o = 0; o < 256; ++o) s += bv[o] * W8[o];
    c0[0] = s + b8[0];
  }
}

// ---- transpose latents [B][256][N] -> fp16 [B][N][256] ----
extern "C" __global__ void transp(const float* __restrict__ latents,
                                  unsigned short* __restrict__ Lt, int N) {
  __shared__ unsigned short tile[256][68];
  const int b = blockIdx.y, n0 = blockIdx.x * 64, tid = threadIdx.x;
  const int nl = tid & 63;
  union { _Float16 h; unsigned short u; } cv;
  for (int c = tid >> 6; c < 256; c += 4) {
    const int n = n0 + nl;
    float v = (n < N) ? latents[((size_t)b * NLAT + c) * N + n] : 0.f;
    cv.h = (_Float16)v;
    tile[c][nl] = cv.u;
  }
  __syncthreads();
  const int nr = tid >> 2, cg = (tid & 3) * 64;
  const int n = n0 + nr;
  if (n < N) {
    for (int cc = 0; cc < 64; cc += 8) {
      f16x8 v;
#pragma unroll
      for (int j = 0; j < 8; ++j) {
        union { unsigned short u; _Float16 h; } bk;
        bk.u = tile[cg + cc + j][nr];
        v[j] = bk.h;
      }
      *(f16x8*)((_Float16*)Lt + ((size_t)b * N + n) * NLAT + cg + cc) = v;
    }
  }
}

extern "C" void kernel_launch(void* const* d_in, const int* in_sizes, int n_in,
                              void* d_out, int out_size, void* d_ws, size_t ws_size,
                              hipStream_t stream) {
  (void)n_in; (void)out_size;
  const float* latents = (const float*)d_in[0];
  const float* pts     = (const float*)d_in[1];
  const float* ptsq    = (const float*)d_in[2];
  const void*  proj    = d_in[3];
  const float* W1 = (const float*)d_in[4];  const float* b1 = (const float*)d_in[5];
  const float* W2 = (const float*)d_in[6];  const float* b2 = (const float*)d_in[7];
  const float* W3 = (const float*)d_in[8];  const float* b3 = (const float*)d_in[9];
  const float* Wq = (const float*)d_in[10]; const float* bq = (const float*)d_in[11];
  const float* Wv = (const float*)d_in[12]; const float* bv = (const float*)d_in[13];
  const float* W8 = (const float*)d_in[14]; const float* b8 = (const float*)d_in[15];
  float* out = (float*)d_out;

  const int B  = 2;
  const int N  = in_sizes[1] / (3 * B);
  const int NQ = in_sizes[2] / (3 * B);

  size_t off = 0;
  auto alloc = [&](size_t bytes) -> char* {
    char* p = (char*)d_ws + off;
    off += (bytes + 255) & ~(size_t)255;
    return p;
  };
  unsigned short* W1p = (unsigned short*)alloc(65536 * 2);
  unsigned short* W2p = (unsigned short*)alloc(65536 * 2);
  unsigned short* W3p = (unsigned short*)alloc(65536 * 2);
  unsigned short* Wqh = (unsigned short*)alloc(16384 * 2);
  float* wv8 = (float*)alloc(256 * 4);
  float* c0  = (float*)alloc(4);
  const size_t lt_bytes = (size_t)B * N * NLAT * 2;
  unsigned short* Lt = (unsigned short*)((char*)d_ws + off);
  const int use_lt = (off + lt_bytes <= ws_size) ? 1 : 0;

  hipLaunchKernelGGL(prep_w, dim3(256), dim3(256), 0, stream,
                     W1, W2, W3, Wq, Wv, W8, bv, b8, W1p, W2p, W3p, Wqh, wv8, c0);
  if (use_lt)
    hipLaunchKernelGGL(transp, dim3((N + 63) / 64, B), dim3(256), 0, stream,
                       latents, Lt, N);
  const int nblocks = (B * NQ + QB - 1) / QB;
  hipLaunchKernelGGL(interp_mfma, dim3(nblocks), dim3(256), 0, stream,
                     latents, pts, ptsq, proj, Lt, W1, W1p, W2p, W3p, Wqh,
                     b1, b2, b3, bq, wv8, c0, out, N, NQ, use_lt);
}